// Round 1
// 12361.048 us; speedup vs baseline: 2.0154x; 2.0154x over previous
//
#include <hip/hip_runtime.h>
#include <hip/hip_bf16.h>
#include <math.h>

// ---- problem dims ----
#define Bz  4
#define Sz  1024
#define Dz  768
#define Hz  12
#define HDz 64
#define Lz  4
#define Vz  8000
#define FFz 3072
#define BSz (Bz*Sz)            // 4096 rows
#define EPSz 1e-5f
#define NEG_BIG (-1e30f)

typedef __hip_bfloat16 bf16;
typedef short  bf16x8 __attribute__((ext_vector_type(8)));   // 8 bf16 (4 VGPR)
typedef float  f32x16 __attribute__((ext_vector_type(16)));  // MFMA 32x32 acc

__device__ __forceinline__ float bf2f(unsigned int u) {
    union { unsigned int i; float f; } c; c.i = u << 16; return c.f;
}
__device__ __forceinline__ float tof(bf16 v)  { return __bfloat162float(v); }
__device__ __forceinline__ float tof(float v) { return v; }
__device__ __forceinline__ void stw(bf16* p, float v)  { *p = __float2bfloat16(v); }
__device__ __forceinline__ void stw(float* p, float v) { *p = v; }

// fp32 -> bf16 bits, round-to-nearest-even
__device__ __forceinline__ unsigned short f2bf(float f) {
    union { float f; unsigned int u; } a; a.f = f;
    unsigned int u = a.u;
    return (unsigned short)((u + 0x7fffu + ((u >> 16) & 1u)) >> 16);
}

// 8-contiguous-element load -> float[8] (16B for bf16, 32B for float)
__device__ __forceinline__ void ld8(const bf16* p, float* o) {
    uint4 u = *(const uint4*)p;
    o[0]=bf2f(u.x&0xffffu); o[1]=bf2f(u.x>>16);
    o[2]=bf2f(u.y&0xffffu); o[3]=bf2f(u.y>>16);
    o[4]=bf2f(u.z&0xffffu); o[5]=bf2f(u.z>>16);
    o[6]=bf2f(u.w&0xffffu); o[7]=bf2f(u.w>>16);
}
__device__ __forceinline__ void ld8(const float* p, float* o) {
    float4 a = *(const float4*)p, b = *(const float4*)(p + 4);
    o[0]=a.x; o[1]=a.y; o[2]=a.z; o[3]=a.w;
    o[4]=b.x; o[5]=b.y; o[6]=b.z; o[7]=b.w;
}

// ---------------- dtype probe: flag=0 -> inputs bf16, flag=1 -> inputs fp32 ----------------
__global__ void __launch_bounds__(256) detect_kernel(const unsigned short* __restrict__ w,
                                                     int* __restrict__ flag) {
    __shared__ int sh[256];
    int cnt = 0;
    for (int i = threadIdx.x; i < 4096; i += 256) {
        float a = fabsf(bf2f((unsigned int)w[i]));
        if (!(a < 1.0f)) cnt++;   // also counts NaN
    }
    sh[threadIdx.x] = cnt; __syncthreads();
    for (int s = 128; s > 0; s >>= 1) {
        if (threadIdx.x < s) sh[threadIdx.x] += sh[threadIdx.x + s];
        __syncthreads();
    }
    if (threadIdx.x == 0) flag[0] = (sh[0] > 100) ? 1 : 0;
}

// ---------------- embedding: x = emb[tok] + pos (fp32 out) ----------------
template<typename WT>
__global__ void __launch_bounds__(256) embed_kernel(const int* __restrict__ flag, int want,
                                                    const int* __restrict__ tok,
                                                    const WT* __restrict__ emb,
                                                    const WT* __restrict__ pos,
                                                    float* __restrict__ out) {
    if (flag[0] != want) return;
    int idx = blockIdx.x * 256 + threadIdx.x;      // over BSz*Dz (exact multiple)
    int d  = idx % Dz;
    int bs = idx / Dz;
    int s  = bs & (Sz - 1);
    int t  = tok[bs];
    out[idx] = tof(emb[(size_t)t * Dz + d]) + tof(pos[(size_t)s * Dz + d]);
}

// ---------------- layernorm: fp32 in, bf16 out; one block per row ----------------
template<typename WT>
__global__ void __launch_bounds__(256) ln_kernel(const int* __restrict__ flag, int want,
                                                 const float* __restrict__ x,
                                                 const WT* __restrict__ g,
                                                 const WT* __restrict__ b,
                                                 bf16* __restrict__ y) {
    if (flag[0] != want) return;
    int row = blockIdx.x;
    const float* xr = x + (size_t)row * Dz;
    float vals[3];
    float s0 = 0.f, s1 = 0.f;
#pragma unroll
    for (int i = 0; i < 3; i++) {
        float v = xr[threadIdx.x + i * 256];
        vals[i] = v; s0 += v; s1 += v * v;
    }
#pragma unroll
    for (int off = 32; off > 0; off >>= 1) {
        s0 += __shfl_down(s0, off);
        s1 += __shfl_down(s1, off);
    }
    __shared__ float r0[4], r1[4];
    __shared__ float mean_s, inv_s;
    int wid = threadIdx.x >> 6, lane = threadIdx.x & 63;
    if (lane == 0) { r0[wid] = s0; r1[wid] = s1; }
    __syncthreads();
    if (threadIdx.x == 0) {
        float a = r0[0] + r0[1] + r0[2] + r0[3];
        float c = r1[0] + r1[1] + r1[2] + r1[3];
        float mean = a * (1.f / Dz);
        float var  = fmaxf(c * (1.f / Dz) - mean * mean, 0.f);
        mean_s = mean;
        inv_s  = rsqrtf(var + EPSz);
    }
    __syncthreads();
    float mean = mean_s, inv = inv_s;
#pragma unroll
    for (int i = 0; i < 3; i++) {
        int cc = threadIdx.x + i * 256;
        y[(size_t)row * Dz + cc] =
            __float2bfloat16((vals[i] - mean) * inv * tof(g[cc]) + tof(b[cc]));
    }
}

// ---------------- GEMM: C[M,N] = act(A[M,K] @ W[K,N] + bias) ----------------
// A bf16 activations, W/bias WT, fp32 accumulate. 128x128 tile, 256 thr, 8x8/thread.
template<typename WT, bool RELU, int OM>
__global__ void __launch_bounds__(256) gemm_kernel(const int* __restrict__ flag, int want,
                                                   const bf16* __restrict__ A,
                                                   const WT* __restrict__ W,
                                                   const WT* __restrict__ bias,
                                                   bf16* __restrict__ Cb,
                                                   float* __restrict__ Cf,
                                                   WT* __restrict__ Co,
                                                   int M, int N, int K) {
    if (flag[0] != want) return;
    __shared__ float As[16][128];   // [k][m]
    __shared__ float Bs[16][128];   // [k][n]
    const int t  = threadIdx.x;
    const int tx = t & 15, ty = t >> 4;
    const int m0 = blockIdx.y << 7, n0 = blockIdx.x << 7;
    const int ar = t >> 1, ak = (t & 1) << 3;      // A-tile load coords
    const int br = t >> 4, bc = (t & 15) << 3;     // W-tile load coords
    const int wn = n0 + bc;

    float acc[8][8];
#pragma unroll
    for (int i = 0; i < 8; i++)
#pragma unroll
        for (int j = 0; j < 8; j++) acc[i][j] = 0.f;

    for (int k0 = 0; k0 < K; k0 += 16) {
        float av[8];
        ld8(A + (size_t)(m0 + ar) * K + (k0 + ak), av);
#pragma unroll
        for (int i = 0; i < 8; i++) As[ak + i][ar] = av[i];
        float bv[8];
        if (wn + 8 <= N) {
            ld8(W + (size_t)(k0 + br) * N + wn, bv);
        } else {
#pragma unroll
            for (int j = 0; j < 8; j++)
                bv[j] = (wn + j < N) ? tof(W[(size_t)(k0 + br) * N + wn + j]) : 0.f;
        }
        *(float4*)&Bs[br][bc]     = make_float4(bv[0], bv[1], bv[2], bv[3]);
        *(float4*)&Bs[br][bc + 4] = make_float4(bv[4], bv[5], bv[6], bv[7]);
        __syncthreads();
#pragma unroll
        for (int kk = 0; kk < 16; kk++) {
            float a[8], b[8];
            *(float4*)(a)     = *(const float4*)&As[kk][ty << 3];
            *(float4*)(a + 4) = *(const float4*)&As[kk][(ty << 3) + 4];
            *(float4*)(b)     = *(const float4*)&Bs[kk][tx << 3];
            *(float4*)(b + 4) = *(const float4*)&Bs[kk][(tx << 3) + 4];
#pragma unroll
            for (int i = 0; i < 8; i++)
#pragma unroll
                for (int j = 0; j < 8; j++)
                    acc[i][j] = fmaf(a[i], b[j], acc[i][j]);
        }
        __syncthreads();
    }
#pragma unroll
    for (int j = 0; j < 8; j++) {
        int n = n0 + (tx << 3) + j;
        if (n >= N) continue;
        float bsv = tof(bias[n]);
#pragma unroll
        for (int i = 0; i < 8; i++) {
            int m = m0 + (ty << 3) + i;
            float v = acc[i][j] + bsv;
            if (RELU) v = fmaxf(v, 0.f);
            if (OM == 0)      Cb[(size_t)m * N + n] = __float2bfloat16(v);
            else if (OM == 1) Cf[(size_t)m * N + n] += v;
            else              stw(Co + ((size_t)m * N + n), v);
        }
    }
}

// ---------------- V transpose: Vt[d][b*S + s] = V[b*S + s][d] (bf16) ----------------
// Coalesced 128B column loads, one 16B store per thread. ~12 MB moved.
__global__ void __launch_bounds__(256) vtrans_kernel(const int* __restrict__ flag, int want,
                                                     const bf16* __restrict__ V,
                                                     bf16* __restrict__ Vt) {
    if (flag[0] != want) return;
    int tid = blockIdx.x * 256 + threadIdx.x;     // BSz*Dz/8 threads exactly
    int d  = tid % Dz;
    int m0 = (tid / Dz) << 3;
    const unsigned short* vs = (const unsigned short*)V;
    unsigned int w[4];
#pragma unroll
    for (int i = 0; i < 4; i++) {
        unsigned int lo = vs[(size_t)(m0 + 2*i)     * Dz + d];
        unsigned int hi = vs[(size_t)(m0 + 2*i + 1) * Dz + d];
        w[i] = lo | (hi << 16);
    }
    *(uint4*)((unsigned short*)Vt + (size_t)d * BSz + m0) = make_uint4(w[0], w[1], w[2], w[3]);
}

// ---------------- MFMA flash attention ----------------
// One wave = 32 q-rows of one (b,h). 2 waves / 128-thr block -> 768 blocks.
// All MFMAs are v_mfma_f32_32x32x16_bf16 with swapped operands:
//   S^T = mfma(A=K_tile, B=Q_tile)   -> lane owns q-col = lane&31 (scores)
//   O^T = mfma(A=V^T_tile, B=P^T)    -> lane owns q-col = lane&31 (output)
// so running max/sum are scalar-per-lane; only 1 shfl_xor(32) per reduce.
// A/B frag: row/col = lane&31, k = 8*(lane>>5)+e (8 consecutive).
// C/D frag: col = lane&31, row = (reg&3) + 8*(reg>>2) + 4*(lane>>5).
template<int CAUSAL>
__global__ void __launch_bounds__(128) attn_mfma_kernel(const int* __restrict__ flag, int want,
                                                        const bf16* __restrict__ Q,
                                                        const bf16* __restrict__ K,
                                                        const bf16* __restrict__ Vt,
                                                        bf16* __restrict__ O) {
    if (flag[0] != want) return;
    __shared__ alignas(16) unsigned short pbuf[2][32][40];   // P[q][k] per wave, 5 KB

    const int wid  = threadIdx.x >> 6;
    const int lane = threadIdx.x & 63;
    const int cq = lane & 31;          // q-col / k-row / d-row depending on frag
    const int h2 = lane >> 5;

    int gw = blockIdx.x * 2 + wid;     // over B*H*(S/32) = 1536
    int qt = gw & 31;                  // q-tile
    int bh = gw >> 5;
    int h = bh % Hz, b = bh / Hz;
    const int q0 = qt << 5;
    const int hoff = h * HDz;

    // Q fragments (B operand), pre-scaled by HD^-0.5 = 0.125 (exact in bf16)
    const bf16* qp = Q + (size_t)(b * Sz + q0 + cq) * Dz + hoff + 8 * h2;
    bf16x8 qf0, qf1, qf2, qf3;
    {
        bf16x8* qfs[4] = { &qf0, &qf1, &qf2, &qf3 };
#pragma unroll
        for (int s = 0; s < 4; s++) {
            uint4 u = *(const uint4*)(qp + 16 * s);
            unsigned int w[4] = { u.x, u.y, u.z, u.w };
            bf16x8 r;
#pragma unroll
            for (int i = 0; i < 4; i++) {
                r[2*i]   = (short)f2bf(bf2f(w[i] & 0xffffu) * 0.125f);
                r[2*i+1] = (short)f2bf(bf2f(w[i] >> 16)     * 0.125f);
            }
            *qfs[s] = r;
        }
    }

    f32x16 oacc0, oacc1;
#pragma unroll
    for (int i = 0; i < 16; i++) { oacc0[i] = 0.f; oacc1[i] = 0.f; }
    float m = NEG_BIG, lsum = 0.f;

    const int nkb = CAUSAL ? (qt + 1) : (Sz >> 5);
    for (int kb = 0; kb < nkb; kb++) {
        const int k0 = kb << 5;
        // K fragments (A operand): row = k-row = cq, kdim d = 16s + 8*h2 + e
        const bf16* kp = K + (size_t)(b * Sz + k0 + cq) * Dz + hoff + 8 * h2;
        bf16x8 kf0 = *(const bf16x8*)(kp);
        bf16x8 kf1 = *(const bf16x8*)(kp + 16);
        bf16x8 kf2 = *(const bf16x8*)(kp + 32);
        bf16x8 kf3 = *(const bf16x8*)(kp + 48);
        // V^T fragments (A operand of PV): row = d = cq (+32), kdim k = 16s + 8*h2 + e
        const bf16* vp  = Vt + (size_t)(hoff + cq) * BSz + (size_t)b * Sz + k0 + 8 * h2;
        const bf16* vp1 = vp + (size_t)32 * BSz;
        bf16x8 va0 = *(const bf16x8*)(vp);
        bf16x8 va1 = *(const bf16x8*)(vp + 16);
        bf16x8 vb0 = *(const bf16x8*)(vp1);
        bf16x8 vb1 = *(const bf16x8*)(vp1 + 16);

        // ---- S^T = K Q^T (scaled): col = q, row = k-local ----
        f32x16 st;
#pragma unroll
        for (int i = 0; i < 16; i++) st[i] = 0.f;
        st = __builtin_amdgcn_mfma_f32_32x32x16_bf16(kf0, qf0, st, 0, 0, 0);
        st = __builtin_amdgcn_mfma_f32_32x32x16_bf16(kf1, qf1, st, 0, 0, 0);
        st = __builtin_amdgcn_mfma_f32_32x32x16_bf16(kf2, qf2, st, 0, 0, 0);
        st = __builtin_amdgcn_mfma_f32_32x32x16_bf16(kf3, qf3, st, 0, 0, 0);

        if (CAUSAL && kb == qt) {
#pragma unroll
            for (int r = 0; r < 16; r++) {
                int kl = (r & 3) + 8 * (r >> 2) + 4 * h2;
                if (kl > cq) st[r] = NEG_BIG;
            }
        }

        // ---- online softmax (per lane = per q-row; half the k's, pair at lane^32) ----
        float tm = st[0];
#pragma unroll
        for (int r = 1; r < 16; r++) tm = fmaxf(tm, st[r]);
        tm = fmaxf(tm, __shfl_xor(tm, 32));
        float mnew = fmaxf(m, tm);
        float sc = __expf(m - mnew);
        m = mnew;
        lsum *= sc;
#pragma unroll
        for (int i = 0; i < 16; i++) { oacc0[i] *= sc; oacc1[i] *= sc; }

        // P = exp(st - m), pack to bf16, write P[q][k] rows to LDS (4x ds_write_b64)
#pragma unroll
        for (int grp = 0; grp < 4; grp++) {
            float p0 = __expf(st[4*grp + 0] - m);
            float p1 = __expf(st[4*grp + 1] - m);
            float p2 = __expf(st[4*grp + 2] - m);
            float p3 = __expf(st[4*grp + 3] - m);
            lsum += (p0 + p1) + (p2 + p3);
            unsigned int w0 = (unsigned int)f2bf(p0) | ((unsigned int)f2bf(p1) << 16);
            unsigned int w1 = (unsigned int)f2bf(p2) | ((unsigned int)f2bf(p3) << 16);
            *(uint2*)&pbuf[wid][cq][8 * grp + 4 * h2] = make_uint2(w0, w1);
        }
        __asm__ __volatile__("" ::: "memory");   // pin LDS write->read order (TBAA)

        // P^T fragments (B operand): col = q = cq, kdim = 16s + 8*h2 + e
        bf16x8 pf0 = *(const bf16x8*)&pbuf[wid][cq][8 * h2];
        bf16x8 pf1 = *(const bf16x8*)&pbuf[wid][cq][16 + 8 * h2];

        // ---- O^T += V^T P^T ----
        oacc0 = __builtin_amdgcn_mfma_f32_32x32x16_bf16(va0, pf0, oacc0, 0, 0, 0);
        oacc0 = __builtin_amdgcn_mfma_f32_32x32x16_bf16(va1, pf1, oacc0, 0, 0, 0);
        oacc1 = __builtin_amdgcn_mfma_f32_32x32x16_bf16(vb0, pf0, oacc1, 0, 0, 0);
        oacc1 = __builtin_amdgcn_mfma_f32_32x32x16_bf16(vb1, pf1, oacc1, 0, 0, 0);
    }

    // ---- finalize: lane owns q-row q0+cq entirely ----
    lsum += __shfl_xor(lsum, 32);
    float inv = 1.f / lsum;
    bf16* ob = O + (size_t)(b * Sz + q0 + cq) * Dz + hoff;
#pragma unroll
    for (int r = 0; r < 16; r++) {
        int d = (r & 3) + 8 * (r >> 2) + 4 * h2;
        ob[d]      = __float2bfloat16(oacc0[r] * inv);
        ob[d + 32] = __float2bfloat16(oacc1[r] * inv);
    }
}

// ---------------- whole network for one dtype-world ----------------
template<typename WT>
static void run_net(void* const* d_in, int want, int* flag,
                    float* x, bf16* xn, bf16* memb,
                    bf16* q, bf16* k, bf16* v, bf16* ao, bf16* hbuf,
                    WT* out, hipStream_t stream) {
    const int* src    = (const int*)d_in[0];
    const int* target = (const int*)d_in[2];
    const WT* src_emb = (const WT*)d_in[4];
    const WT* tgt_emb = (const WT*)d_in[5];
    const WT* pos_emb = (const WT*)d_in[6];
    const WT* eaw = (const WT*)d_in[7];
    const WT* eab = (const WT*)d_in[8];
    const WT* elg = (const WT*)d_in[9];
    const WT* elb = (const WT*)d_in[10];
    const WT* ew1 = (const WT*)d_in[11];
    const WT* eb1 = (const WT*)d_in[12];
    const WT* ew2 = (const WT*)d_in[13];
    const WT* eb2 = (const WT*)d_in[14];
    const WT* eng = (const WT*)d_in[15];
    const WT* enb = (const WT*)d_in[16];
    const WT* daw = (const WT*)d_in[17];
    const WT* dab = (const WT*)d_in[18];
    const WT* dlg = (const WT*)d_in[19];
    const WT* dlb = (const WT*)d_in[20];
    const WT* dw1 = (const WT*)d_in[21];
    const WT* db1 = (const WT*)d_in[22];
    const WT* dw2 = (const WT*)d_in[23];
    const WT* db2 = (const WT*)d_in[24];
    const WT* dng = (const WT*)d_in[25];
    const WT* dnb = (const WT*)d_in[26];
    const WT* outw = (const WT*)d_in[27];
    const WT* outb = (const WT*)d_in[28];

    const size_t DD = (size_t)Dz * Dz;
    dim3 blk(256);
    bf16* Vt = xn;   // xn is dead between the V-projection and the next LN write
    auto gemm = [&](const bf16* A, const WT* W, const WT* bias,
                    bf16* CbP, float* CfP, WT* CoP, int M, int N, int K, int mode) {
        dim3 grid((N + 127) / 128, M / 128);
        if (mode == 0)
            gemm_kernel<WT, false, 0><<<grid, blk, 0, stream>>>(flag, want, A, W, bias, CbP, nullptr, nullptr, M, N, K);
        else if (mode == 1)
            gemm_kernel<WT, true, 0><<<grid, blk, 0, stream>>>(flag, want, A, W, bias, CbP, nullptr, nullptr, M, N, K);
        else if (mode == 2)
            gemm_kernel<WT, false, 1><<<grid, blk, 0, stream>>>(flag, want, A, W, bias, nullptr, CfP, nullptr, M, N, K);
        else
            gemm_kernel<WT, false, 2><<<grid, blk, 0, stream>>>(flag, want, A, W, bias, nullptr, nullptr, CoP, M, N, K);
    };
    auto attn = [&](int causal) {
        vtrans_kernel<<<BSz * Dz / 8 / 256, blk, 0, stream>>>(flag, want, v, Vt);
        if (causal)
            attn_mfma_kernel<1><<<Bz * Hz * (Sz / 32) / 2, dim3(128), 0, stream>>>(flag, want, q, k, Vt, ao);
        else
            attn_mfma_kernel<0><<<Bz * Hz * (Sz / 32) / 2, dim3(128), 0, stream>>>(flag, want, q, k, Vt, ao);
    };

    // ================= encoder =================
    embed_kernel<WT><<<BSz * Dz / 256, blk, 0, stream>>>(flag, want, src, src_emb, pos_emb, x);
    for (int l = 0; l < Lz; l++) {
        const WT* w  = eaw + (size_t)l * 4 * DD;
        const WT* bb = eab + (size_t)l * 4 * Dz;
        ln_kernel<WT><<<BSz, blk, 0, stream>>>(flag, want, x, elg + (size_t)(l * 2) * Dz, elb + (size_t)(l * 2) * Dz, xn);
        gemm(xn, w + 0 * DD, bb + 0 * Dz, q, nullptr, nullptr, BSz, Dz, Dz, 0);
        gemm(xn, w + 1 * DD, bb + 1 * Dz, k, nullptr, nullptr, BSz, Dz, Dz, 0);
        gemm(xn, w + 2 * DD, bb + 2 * Dz, v, nullptr, nullptr, BSz, Dz, Dz, 0);
        attn(0);
        gemm(ao, w + 3 * DD, bb + 3 * Dz, nullptr, x, nullptr, BSz, Dz, Dz, 2);
        ln_kernel<WT><<<BSz, blk, 0, stream>>>(flag, want, x, elg + (size_t)(l * 2 + 1) * Dz, elb + (size_t)(l * 2 + 1) * Dz, xn);
        gemm(xn, ew1 + (size_t)l * Dz * FFz, eb1 + (size_t)l * FFz, hbuf, nullptr, nullptr, BSz, FFz, Dz, 1);
        gemm(hbuf, ew2 + (size_t)l * FFz * Dz, eb2 + (size_t)l * Dz, nullptr, x, nullptr, BSz, Dz, FFz, 2);
    }
    ln_kernel<WT><<<BSz, blk, 0, stream>>>(flag, want, x, eng, enb, memb);

    // ================= decoder =================
    embed_kernel<WT><<<BSz * Dz / 256, blk, 0, stream>>>(flag, want, target, tgt_emb, pos_emb, x);
    for (int l = 0; l < Lz; l++) {
        const WT* w  = daw + (size_t)l * 8 * DD;
        const WT* bb = dab + (size_t)l * 8 * Dz;
        // self-attention (causal)
        ln_kernel<WT><<<BSz, blk, 0, stream>>>(flag, want, x, dlg + (size_t)(l * 3) * Dz, dlb + (size_t)(l * 3) * Dz, xn);
        gemm(xn, w + 0 * DD, bb + 0 * Dz, q, nullptr, nullptr, BSz, Dz, Dz, 0);
        gemm(xn, w + 1 * DD, bb + 1 * Dz, k, nullptr, nullptr, BSz, Dz, Dz, 0);
        gemm(xn, w + 2 * DD, bb + 2 * Dz, v, nullptr, nullptr, BSz, Dz, Dz, 0);
        attn(1);
        gemm(ao, w + 3 * DD, bb + 3 * Dz, nullptr, x, nullptr, BSz, Dz, Dz, 2);
        // cross-attention
        ln_kernel<WT><<<BSz, blk, 0, stream>>>(flag, want, x, dlg + (size_t)(l * 3 + 1) * Dz, dlb + (size_t)(l * 3 + 1) * Dz, xn);
        gemm(xn,   w + 4 * DD, bb + 4 * Dz, q, nullptr, nullptr, BSz, Dz, Dz, 0);
        gemm(memb, w + 5 * DD, bb + 5 * Dz, k, nullptr, nullptr, BSz, Dz, Dz, 0);
        gemm(memb, w + 6 * DD, bb + 6 * Dz, v, nullptr, nullptr, BSz, Dz, Dz, 0);
        attn(0);
        gemm(ao, w + 7 * DD, bb + 7 * Dz, nullptr, x, nullptr, BSz, Dz, Dz, 2);
        // ffn
        ln_kernel<WT><<<BSz, blk, 0, stream>>>(flag, want, x, dlg + (size_t)(l * 3 + 2) * Dz, dlb + (size_t)(l * 3 + 2) * Dz, xn);
        gemm(xn, dw1 + (size_t)l * Dz * FFz, db1 + (size_t)l * FFz, hbuf, nullptr, nullptr, BSz, FFz, Dz, 1);
        gemm(hbuf, dw2 + (size_t)l * FFz * Dz, db2 + (size_t)l * Dz, nullptr, x, nullptr, BSz, Dz, FFz, 2);
    }
    ln_kernel<WT><<<BSz, blk, 0, stream>>>(flag, want, x, dng, dnb, xn);

    // ================= output projection =================
    gemm(xn, outw, outb, nullptr, nullptr, out, BSz, Vz, Dz, 3);
}

// ---------------- launcher ----------------
extern "C" void kernel_launch(void* const* d_in, const int* in_sizes, int n_in,
                              void* d_out, int out_size, void* d_ws, size_t ws_size,
                              hipStream_t stream) {
    const size_t SD = (size_t)BSz * Dz;        // 3,145,728 elements
    char* wsb = (char*)d_ws;
    int*   flag = (int*)wsb;                                   // 256 B reserved
    float* x    = (float*)(wsb + 256);                         // SD fp32
    bf16*  xn   = (bf16*)(wsb + 256 + SD * 4);                 // SD bf16 (doubles as Vt)
    bf16*  memb = xn + SD;                                     // SD bf16
    bf16*  big  = memb + SD;                                   // 4*SD bf16
    bf16 *q = big, *k = big + SD, *v = big + 2 * SD, *ao = big + 3 * SD;
    bf16* hbuf = big;                                          // BSz*FFz == 4*SD, aliases q/k/v/ao
    // total ws use: 256 + 4*SD + 2*2*SD + 2*4*SD = ~50.4 MB

    detect_kernel<<<1, 256, 0, stream>>>((const unsigned short*)d_in[4], flag);
    run_net<bf16 >(d_in, 0, flag, x, xn, memb, q, k, v, ao, hbuf, (bf16*)d_out, stream);
    run_net<float>(d_in, 1, flag, x, xn, memb, q, k, v, ao, hbuf, (float*)d_out, stream);
}

// Round 2
// 6308.926 us; speedup vs baseline: 3.9487x; 1.9593x over previous
//
#include <hip/hip_runtime.h>
#include <hip/hip_bf16.h>
#include <math.h>

// ---- problem dims ----
#define Bz  4
#define Sz  1024
#define Dz  768
#define Hz  12
#define HDz 64
#define Lz  4
#define Vz  8000
#define FFz 3072
#define BSz (Bz*Sz)            // 4096 rows
#define EPSz 1e-5f
#define NEG_BIG (-1e30f)

typedef __hip_bfloat16 bf16;
typedef short  bf16x8 __attribute__((ext_vector_type(8)));   // 8 bf16 (4 VGPR)
typedef float  f32x16 __attribute__((ext_vector_type(16)));  // MFMA 32x32 acc

__device__ __forceinline__ float bf2f(unsigned int u) {
    union { unsigned int i; float f; } c; c.i = u << 16; return c.f;
}
__device__ __forceinline__ float tof(bf16 v)  { return __bfloat162float(v); }
__device__ __forceinline__ float tof(float v) { return v; }
__device__ __forceinline__ void stw(bf16* p, float v)  { *p = __float2bfloat16(v); }
__device__ __forceinline__ void stw(float* p, float v) { *p = v; }

// fp32 -> bf16 bits, round-to-nearest-even
__device__ __forceinline__ unsigned short f2bf(float f) {
    union { float f; unsigned int u; } a; a.f = f;
    unsigned int u = a.u;
    return (unsigned short)((u + 0x7fffu + ((u >> 16) & 1u)) >> 16);
}
__device__ __forceinline__ uint4 pack8(const unsigned short* s) {
    return make_uint4((unsigned)s[0] | ((unsigned)s[1] << 16),
                      (unsigned)s[2] | ((unsigned)s[3] << 16),
                      (unsigned)s[4] | ((unsigned)s[5] << 16),
                      (unsigned)s[6] | ((unsigned)s[7] << 16));
}

// 8-contiguous-element load -> float[8]
__device__ __forceinline__ void ld8(const bf16* p, float* o) {
    uint4 u = *(const uint4*)p;
    o[0]=bf2f(u.x&0xffffu); o[1]=bf2f(u.x>>16);
    o[2]=bf2f(u.y&0xffffu); o[3]=bf2f(u.y>>16);
    o[4]=bf2f(u.z&0xffffu); o[5]=bf2f(u.z>>16);
    o[6]=bf2f(u.w&0xffffu); o[7]=bf2f(u.w>>16);
}
__device__ __forceinline__ void ld8(const float* p, float* o) {
    float4 a = *(const float4*)p, b = *(const float4*)(p + 4);
    o[0]=a.x; o[1]=a.y; o[2]=a.z; o[3]=a.w;
    o[4]=b.x; o[5]=b.y; o[6]=b.z; o[7]=b.w;
}

// ---------------- dtype probe: flag=0 -> inputs bf16, flag=1 -> inputs fp32 ----------------
__global__ void __launch_bounds__(256) detect_kernel(const unsigned short* __restrict__ w,
                                                     int* __restrict__ flag) {
    __shared__ int sh[256];
    int cnt = 0;
    for (int i = threadIdx.x; i < 4096; i += 256) {
        float a = fabsf(bf2f((unsigned int)w[i]));
        if (!(a < 1.0f)) cnt++;   // also counts NaN
    }
    sh[threadIdx.x] = cnt; __syncthreads();
    for (int s = 128; s > 0; s >>= 1) {
        if (threadIdx.x < s) sh[threadIdx.x] += sh[threadIdx.x + s];
        __syncthreads();
    }
    if (threadIdx.x == 0) flag[0] = (sh[0] > 100) ? 1 : 0;
}

// ---------------- embedding: x = emb[tok] + pos (fp32 out) ----------------
template<typename WT>
__global__ void __launch_bounds__(256) embed_kernel(const int* __restrict__ flag, int want,
                                                    const int* __restrict__ tok,
                                                    const WT* __restrict__ emb,
                                                    const WT* __restrict__ pos,
                                                    float* __restrict__ out) {
    if (flag[0] != want) return;
    int idx = blockIdx.x * 256 + threadIdx.x;      // over BSz*Dz (exact multiple)
    int d  = idx % Dz;
    int bs = idx / Dz;
    int s  = bs & (Sz - 1);
    int t  = tok[bs];
    out[idx] = tof(emb[(size_t)t * Dz + d]) + tof(pos[(size_t)s * Dz + d]);
}

// ---------------- layernorm: fp32 in, bf16 out; one block per row ----------------
template<typename WT>
__global__ void __launch_bounds__(256) ln_kernel(const int* __restrict__ flag, int want,
                                                 const float* __restrict__ x,
                                                 const WT* __restrict__ g,
                                                 const WT* __restrict__ b,
                                                 bf16* __restrict__ y) {
    if (flag[0] != want) return;
    int row = blockIdx.x;
    const float* xr = x + (size_t)row * Dz;
    float vals[3];
    float s0 = 0.f, s1 = 0.f;
#pragma unroll
    for (int i = 0; i < 3; i++) {
        float v = xr[threadIdx.x + i * 256];
        vals[i] = v; s0 += v; s1 += v * v;
    }
#pragma unroll
    for (int off = 32; off > 0; off >>= 1) {
        s0 += __shfl_down(s0, off);
        s1 += __shfl_down(s1, off);
    }
    __shared__ float r0[4], r1[4];
    __shared__ float mean_s, inv_s;
    int wid = threadIdx.x >> 6, lane = threadIdx.x & 63;
    if (lane == 0) { r0[wid] = s0; r1[wid] = s1; }
    __syncthreads();
    if (threadIdx.x == 0) {
        float a = r0[0] + r0[1] + r0[2] + r0[3];
        float c = r1[0] + r1[1] + r1[2] + r1[3];
        float mean = a * (1.f / Dz);
        float var  = fmaxf(c * (1.f / Dz) - mean * mean, 0.f);
        mean_s = mean;
        inv_s  = rsqrtf(var + EPSz);
    }
    __syncthreads();
    float mean = mean_s, inv = inv_s;
#pragma unroll
    for (int i = 0; i < 3; i++) {
        int cc = threadIdx.x + i * 256;
        y[(size_t)row * Dz + cc] =
            __float2bfloat16((vals[i] - mean) * inv * tof(g[cc]) + tof(b[cc]));
    }
}

// ---------------- MFMA GEMM: C[M,N] = act(A[M,K] @ W[K,N] + bias) ----------------
// A bf16 [M,K]; W fp32 (SPLIT: hi+lo bf16 pair, ~2^-17 weight precision) or bf16.
// 128x128 tile, BK=64, 4 waves (2x2), each wave 2x2 v_mfma_f32_32x32x16_bf16 frags.
// LDS rows padded to 72 elems (144B): word-stride 36 => 36n mod 32 sweeps all 8
// bank-groups every 8 rows -> minimal b128 conflicts on both ds_write and ds_read.
// Reg-staged prefetch (T14): next tile's global loads issued right after barrier,
// consumed at next stage() -> HBM/L2 latency hides under the 16-32 MFMAs.
#define BKz 64
#define LDAp 72

template<typename WT, bool RELU, int OM, bool SPLIT>
__global__ void __launch_bounds__(256) gemm_mfma(const int* __restrict__ flag, int want,
                                                 const bf16* __restrict__ A,
                                                 const WT* __restrict__ W,
                                                 const WT* __restrict__ bias,
                                                 bf16* __restrict__ Cb,
                                                 float* __restrict__ Cf,
                                                 WT* __restrict__ Co,
                                                 int M, int N, int K) {
    if (flag[0] != want) return;
    __shared__ alignas(16) unsigned short As[128 * LDAp];
    __shared__ alignas(16) unsigned short Bh[128 * LDAp];
    __shared__ alignas(16) unsigned short Bl[SPLIT ? 128 * LDAp : 16];

    const int t = threadIdx.x;
    const int w = t >> 6, lane = t & 63;
    const int l31 = lane & 31, h2 = lane >> 5;
    const int wr = w >> 1, wc = w & 1;
    const int m0 = blockIdx.y << 7, n0 = blockIdx.x << 7;

    // staging coords
    const int am = t >> 1, ae = (t & 1) << 5;          // A: row, 32-elem half
    const int bn = t & 127, bk0 = t >> 7;              // B: col n, kb parity
    const bool nok = (n0 + bn) < N;

    uint4 areg[4];
    float breg[4][8];

    auto loadA = [&](int k0) {
        const bf16* ap = A + (size_t)(m0 + am) * K + k0 + ae;
#pragma unroll
        for (int i = 0; i < 4; i++) areg[i] = *(const uint4*)(ap + 8 * i);
    };
    auto loadB = [&](int k0) {
        const WT* wp = W + (size_t)k0 * N + n0 + bn;   // lanes sweep consecutive n -> coalesced
#pragma unroll
        for (int c = 0; c < 4; c++) {
            const int kb = bk0 + 2 * c;
#pragma unroll
            for (int e = 0; e < 8; e++)
                breg[c][e] = nok ? tof(wp[(size_t)(8 * kb + e) * N]) : 0.f;
        }
    };
    auto stage = [&]() {
#pragma unroll
        for (int i = 0; i < 4; i++)
            *(uint4*)&As[am * LDAp + ae + 8 * i] = areg[i];
#pragma unroll
        for (int c = 0; c < 4; c++) {
            const int kb = bk0 + 2 * c;
            unsigned short hi[8], lo[8];
#pragma unroll
            for (int e = 0; e < 8; e++) {
                float v = breg[c][e];
                hi[e] = f2bf(v);
                if (SPLIT) lo[e] = f2bf(v - bf2f((unsigned int)hi[e]));
            }
            *(uint4*)&Bh[bn * LDAp + 8 * kb] = pack8(hi);
            if (SPLIT) *(uint4*)&Bl[bn * LDAp + 8 * kb] = pack8(lo);
        }
    };

    f32x16 acc00, acc01, acc10, acc11;
#pragma unroll
    for (int i = 0; i < 16; i++) { acc00[i] = 0.f; acc01[i] = 0.f; acc10[i] = 0.f; acc11[i] = 0.f; }

    const int rb = (wr << 6) + l31, cb = (wc << 6) + l31;
    loadA(0); loadB(0);
    for (int k0 = 0; k0 < K; k0 += BKz) {
        stage();
        __syncthreads();
        if (k0 + BKz < K) { loadA(k0 + BKz); loadB(k0 + BKz); }   // prefetch (issue-early)
#pragma unroll
        for (int kh = 0; kh < 4; kh++) {
            const int ko = (h2 << 3) + (kh << 4);
            bf16x8 a0 = *(const bf16x8*)&As[(rb)      * LDAp + ko];
            bf16x8 a1 = *(const bf16x8*)&As[(rb + 32) * LDAp + ko];
            bf16x8 b0 = *(const bf16x8*)&Bh[(cb)      * LDAp + ko];
            bf16x8 b1 = *(const bf16x8*)&Bh[(cb + 32) * LDAp + ko];
            acc00 = __builtin_amdgcn_mfma_f32_32x32x16_bf16(a0, b0, acc00, 0, 0, 0);
            acc01 = __builtin_amdgcn_mfma_f32_32x32x16_bf16(a0, b1, acc01, 0, 0, 0);
            acc10 = __builtin_amdgcn_mfma_f32_32x32x16_bf16(a1, b0, acc10, 0, 0, 0);
            acc11 = __builtin_amdgcn_mfma_f32_32x32x16_bf16(a1, b1, acc11, 0, 0, 0);
            if (SPLIT) {
                bf16x8 c0 = *(const bf16x8*)&Bl[(cb)      * LDAp + ko];
                bf16x8 c1 = *(const bf16x8*)&Bl[(cb + 32) * LDAp + ko];
                acc00 = __builtin_amdgcn_mfma_f32_32x32x16_bf16(a0, c0, acc00, 0, 0, 0);
                acc01 = __builtin_amdgcn_mfma_f32_32x32x16_bf16(a0, c1, acc01, 0, 0, 0);
                acc10 = __builtin_amdgcn_mfma_f32_32x32x16_bf16(a1, c0, acc10, 0, 0, 0);
                acc11 = __builtin_amdgcn_mfma_f32_32x32x16_bf16(a1, c1, acc11, 0, 0, 0);
            }
        }
        __syncthreads();
    }

    // epilogue: lane owns col n; rows per C/D map row=(r&3)+8*(r>>2)+4*h2
    auto epi = [&](const f32x16& a, int ra, int nb) {
        const int n = n0 + (wc << 6) + (nb << 5) + l31;
        if (n >= N) return;
        const float bs = tof(bias[n]);
#pragma unroll
        for (int r = 0; r < 16; r++) {
            const int m = m0 + (wr << 6) + (ra << 5) + (r & 3) + ((r >> 2) << 3) + (h2 << 2);
            float v = a[r] + bs;
            if (RELU) v = fmaxf(v, 0.f);
            if (OM == 0)      Cb[(size_t)m * N + n] = __float2bfloat16(v);
            else if (OM == 1) Cf[(size_t)m * N + n] += v;
            else              stw(Co + ((size_t)m * N + n), v);
        }
    };
    epi(acc00, 0, 0); epi(acc01, 0, 1); epi(acc10, 1, 0); epi(acc11, 1, 1);
}

// ---------------- V transpose: Vt[d][b*S + s] = V[b*S + s][d] (bf16) ----------------
__global__ void __launch_bounds__(256) vtrans_kernel(const int* __restrict__ flag, int want,
                                                     const bf16* __restrict__ V,
                                                     bf16* __restrict__ Vt) {
    if (flag[0] != want) return;
    int tid = blockIdx.x * 256 + threadIdx.x;     // BSz*Dz/8 threads exactly
    int d  = tid % Dz;
    int m0 = (tid / Dz) << 3;
    const unsigned short* vs = (const unsigned short*)V;
    unsigned int w[4];
#pragma unroll
    for (int i = 0; i < 4; i++) {
        unsigned int lo = vs[(size_t)(m0 + 2*i)     * Dz + d];
        unsigned int hi = vs[(size_t)(m0 + 2*i + 1) * Dz + d];
        w[i] = lo | (hi << 16);
    }
    *(uint4*)((unsigned short*)Vt + (size_t)d * BSz + m0) = make_uint4(w[0], w[1], w[2], w[3]);
}

// ---------------- MFMA flash attention (verified round 0) ----------------
template<int CAUSAL>
__global__ void __launch_bounds__(128) attn_mfma_kernel(const int* __restrict__ flag, int want,
                                                        const bf16* __restrict__ Q,
                                                        const bf16* __restrict__ K,
                                                        const bf16* __restrict__ Vt,
                                                        bf16* __restrict__ O) {
    if (flag[0] != want) return;
    __shared__ alignas(16) unsigned short pbuf[2][32][40];   // P[q][k] per wave, 5 KB

    const int wid  = threadIdx.x >> 6;
    const int lane = threadIdx.x & 63;
    const int cq = lane & 31;
    const int h2 = lane >> 5;

    int gw = blockIdx.x * 2 + wid;     // over B*H*(S/32) = 1536
    int qt = gw & 31;
    int bh = gw >> 5;
    int h = bh % Hz, b = bh / Hz;
    const int q0 = qt << 5;
    const int hoff = h * HDz;

    const bf16* qp = Q + (size_t)(b * Sz + q0 + cq) * Dz + hoff + 8 * h2;
    bf16x8 qf0, qf1, qf2, qf3;
    {
        bf16x8* qfs[4] = { &qf0, &qf1, &qf2, &qf3 };
#pragma unroll
        for (int s = 0; s < 4; s++) {
            uint4 u = *(const uint4*)(qp + 16 * s);
            unsigned int wv[4] = { u.x, u.y, u.z, u.w };
            bf16x8 r;
#pragma unroll
            for (int i = 0; i < 4; i++) {
                r[2*i]   = (short)f2bf(bf2f(wv[i] & 0xffffu) * 0.125f);
                r[2*i+1] = (short)f2bf(bf2f(wv[i] >> 16)     * 0.125f);
            }
            *qfs[s] = r;
        }
    }

    f32x16 oacc0, oacc1;
#pragma unroll
    for (int i = 0; i < 16; i++) { oacc0[i] = 0.f; oacc1[i] = 0.f; }
    float m = NEG_BIG, lsum = 0.f;

    const int nkb = CAUSAL ? (qt + 1) : (Sz >> 5);
    for (int kb = 0; kb < nkb; kb++) {
        const int k0 = kb << 5;
        const bf16* kp = K + (size_t)(b * Sz + k0 + cq) * Dz + hoff + 8 * h2;
        bf16x8 kf0 = *(const bf16x8*)(kp);
        bf16x8 kf1 = *(const bf16x8*)(kp + 16);
        bf16x8 kf2 = *(const bf16x8*)(kp + 32);
        bf16x8 kf3 = *(const bf16x8*)(kp + 48);
        const bf16* vp  = Vt + (size_t)(hoff + cq) * BSz + (size_t)b * Sz + k0 + 8 * h2;
        const bf16* vp1 = vp + (size_t)32 * BSz;
        bf16x8 va0 = *(const bf16x8*)(vp);
        bf16x8 va1 = *(const bf16x8*)(vp + 16);
        bf16x8 vb0 = *(const bf16x8*)(vp1);
        bf16x8 vb1 = *(const bf16x8*)(vp1 + 16);

        f32x16 st;
#pragma unroll
        for (int i = 0; i < 16; i++) st[i] = 0.f;
        st = __builtin_amdgcn_mfma_f32_32x32x16_bf16(kf0, qf0, st, 0, 0, 0);
        st = __builtin_amdgcn_mfma_f32_32x32x16_bf16(kf1, qf1, st, 0, 0, 0);
        st = __builtin_amdgcn_mfma_f32_32x32x16_bf16(kf2, qf2, st, 0, 0, 0);
        st = __builtin_amdgcn_mfma_f32_32x32x16_bf16(kf3, qf3, st, 0, 0, 0);

        if (CAUSAL && kb == qt) {
#pragma unroll
            for (int r = 0; r < 16; r++) {
                int kl = (r & 3) + 8 * (r >> 2) + 4 * h2;
                if (kl > cq) st[r] = NEG_BIG;
            }
        }

        float tm = st[0];
#pragma unroll
        for (int r = 1; r < 16; r++) tm = fmaxf(tm, st[r]);
        tm = fmaxf(tm, __shfl_xor(tm, 32));
        float mnew = fmaxf(m, tm);
        float sc = __expf(m - mnew);
        m = mnew;
        lsum *= sc;
#pragma unroll
        for (int i = 0; i < 16; i++) { oacc0[i] *= sc; oacc1[i] *= sc; }

#pragma unroll
        for (int grp = 0; grp < 4; grp++) {
            float p0 = __expf(st[4*grp + 0] - m);
            float p1 = __expf(st[4*grp + 1] - m);
            float p2 = __expf(st[4*grp + 2] - m);
            float p3 = __expf(st[4*grp + 3] - m);
            lsum += (p0 + p1) + (p2 + p3);
            unsigned int w0 = (unsigned int)f2bf(p0) | ((unsigned int)f2bf(p1) << 16);
            unsigned int w1 = (unsigned int)f2bf(p2) | ((unsigned int)f2bf(p3) << 16);
            *(uint2*)&pbuf[wid][cq][8 * grp + 4 * h2] = make_uint2(w0, w1);
        }
        __asm__ __volatile__("" ::: "memory");   // pin LDS write->read order (TBAA)

        bf16x8 pf0 = *(const bf16x8*)&pbuf[wid][cq][8 * h2];
        bf16x8 pf1 = *(const bf16x8*)&pbuf[wid][cq][16 + 8 * h2];

        oacc0 = __builtin_amdgcn_mfma_f32_32x32x16_bf16(va0, pf0, oacc0, 0, 0, 0);
        oacc0 = __builtin_amdgcn_mfma_f32_32x32x16_bf16(va1, pf1, oacc0, 0, 0, 0);
        oacc1 = __builtin_amdgcn_mfma_f32_32x32x16_bf16(vb0, pf0, oacc1, 0, 0, 0);
        oacc1 = __builtin_amdgcn_mfma_f32_32x32x16_bf16(vb1, pf1, oacc1, 0, 0, 0);
    }

    lsum += __shfl_xor(lsum, 32);
    float inv = 1.f / lsum;
    bf16* ob = O + (size_t)(b * Sz + q0 + cq) * Dz + hoff;
#pragma unroll
    for (int r = 0; r < 16; r++) {
        int d = (r & 3) + 8 * (r >> 2) + 4 * h2;
        ob[d]      = __float2bfloat16(oacc0[r] * inv);
        ob[d + 32] = __float2bfloat16(oacc1[r] * inv);
    }
}

// ---------------- whole network for one dtype-world ----------------
template<typename WT>
static void run_net(void* const* d_in, int want, int* flag,
                    float* x, bf16* xn, bf16* memb,
                    bf16* q, bf16* k, bf16* v, bf16* ao, bf16* hbuf,
                    WT* out, hipStream_t stream) {
    const int* src    = (const int*)d_in[0];
    const int* target = (const int*)d_in[2];
    const WT* src_emb = (const WT*)d_in[4];
    const WT* tgt_emb = (const WT*)d_in[5];
    const WT* pos_emb = (const WT*)d_in[6];
    const WT* eaw = (const WT*)d_in[7];
    const WT* eab = (const WT*)d_in[8];
    const WT* elg = (const WT*)d_in[9];
    const WT* elb = (const WT*)d_in[10];
    const WT* ew1 = (const WT*)d_in[11];
    const WT* eb1 = (const WT*)d_in[12];
    const WT* ew2 = (const WT*)d_in[13];
    const WT* eb2 = (const WT*)d_in[14];
    const WT* eng = (const WT*)d_in[15];
    const WT* enb = (const WT*)d_in[16];
    const WT* daw = (const WT*)d_in[17];
    const WT* dab = (const WT*)d_in[18];
    const WT* dlg = (const WT*)d_in[19];
    const WT* dlb = (const WT*)d_in[20];
    const WT* dw1 = (const WT*)d_in[21];
    const WT* db1 = (const WT*)d_in[22];
    const WT* dw2 = (const WT*)d_in[23];
    const WT* db2 = (const WT*)d_in[24];
    const WT* dng = (const WT*)d_in[25];
    const WT* dnb = (const WT*)d_in[26];
    const WT* outw = (const WT*)d_in[27];
    const WT* outb = (const WT*)d_in[28];

    const size_t DD = (size_t)Dz * Dz;
    dim3 blk(256);
    bf16* Vt = xn;   // xn is dead between the V-projection and the next LN write
    constexpr bool SPL = (sizeof(WT) == 4);
    // mode: 0 store-bf16, 1 relu-store-bf16, 2 add-into-f32, 3 store-WT
    auto gemm = [&](const bf16* A, const WT* W, const WT* bias,
                    bf16* CbP, float* CfP, WT* CoP, int M, int N, int K, int mode) {
        dim3 grid((N + 127) / 128, M / 128);
        if (mode == 0)
            gemm_mfma<WT, false, 0, SPL><<<grid, blk, 0, stream>>>(flag, want, A, W, bias, CbP, nullptr, nullptr, M, N, K);
        else if (mode == 1)
            gemm_mfma<WT, true, 0, SPL><<<grid, blk, 0, stream>>>(flag, want, A, W, bias, CbP, nullptr, nullptr, M, N, K);
        else if (mode == 2)
            gemm_mfma<WT, false, 1, SPL><<<grid, blk, 0, stream>>>(flag, want, A, W, bias, nullptr, CfP, nullptr, M, N, K);
        else
            gemm_mfma<WT, false, 2, SPL><<<grid, blk, 0, stream>>>(flag, want, A, W, bias, nullptr, nullptr, CoP, M, N, K);
    };
    auto attn = [&](int causal) {
        vtrans_kernel<<<BSz * Dz / 8 / 256, blk, 0, stream>>>(flag, want, v, Vt);
        if (causal)
            attn_mfma_kernel<1><<<Bz * Hz * (Sz / 32) / 2, dim3(128), 0, stream>>>(flag, want, q, k, Vt, ao);
        else
            attn_mfma_kernel<0><<<Bz * Hz * (Sz / 32) / 2, dim3(128), 0, stream>>>(flag, want, q, k, Vt, ao);
    };

    // ================= encoder =================
    embed_kernel<WT><<<BSz * Dz / 256, blk, 0, stream>>>(flag, want, src, src_emb, pos_emb, x);
    for (int l = 0; l < Lz; l++) {
        const WT* w  = eaw + (size_t)l * 4 * DD;
        const WT* bb = eab + (size_t)l * 4 * Dz;
        ln_kernel<WT><<<BSz, blk, 0, stream>>>(flag, want, x, elg + (size_t)(l * 2) * Dz, elb + (size_t)(l * 2) * Dz, xn);
        gemm(xn, w + 0 * DD, bb + 0 * Dz, q, nullptr, nullptr, BSz, Dz, Dz, 0);
        gemm(xn, w + 1 * DD, bb + 1 * Dz, k, nullptr, nullptr, BSz, Dz, Dz, 0);
        gemm(xn, w + 2 * DD, bb + 2 * Dz, v, nullptr, nullptr, BSz, Dz, Dz, 0);
        attn(0);
        gemm(ao, w + 3 * DD, bb + 3 * Dz, nullptr, x, nullptr, BSz, Dz, Dz, 2);
        ln_kernel<WT><<<BSz, blk, 0, stream>>>(flag, want, x, elg + (size_t)(l * 2 + 1) * Dz, elb + (size_t)(l * 2 + 1) * Dz, xn);
        gemm(xn, ew1 + (size_t)l * Dz * FFz, eb1 + (size_t)l * FFz, hbuf, nullptr, nullptr, BSz, FFz, Dz, 1);
        gemm(hbuf, ew2 + (size_t)l * FFz * Dz, eb2 + (size_t)l * Dz, nullptr, x, nullptr, BSz, Dz, FFz, 2);
    }
    ln_kernel<WT><<<BSz, blk, 0, stream>>>(flag, want, x, eng, enb, memb);

    // ================= decoder =================
    embed_kernel<WT><<<BSz * Dz / 256, blk, 0, stream>>>(flag, want, target, tgt_emb, pos_emb, x);
    for (int l = 0; l < Lz; l++) {
        const WT* w  = daw + (size_t)l * 8 * DD;
        const WT* bb = dab + (size_t)l * 8 * Dz;
        // self-attention (causal)
        ln_kernel<WT><<<BSz, blk, 0, stream>>>(flag, want, x, dlg + (size_t)(l * 3) * Dz, dlb + (size_t)(l * 3) * Dz, xn);
        gemm(xn, w + 0 * DD, bb + 0 * Dz, q, nullptr, nullptr, BSz, Dz, Dz, 0);
        gemm(xn, w + 1 * DD, bb + 1 * Dz, k, nullptr, nullptr, BSz, Dz, Dz, 0);
        gemm(xn, w + 2 * DD, bb + 2 * Dz, v, nullptr, nullptr, BSz, Dz, Dz, 0);
        attn(1);
        gemm(ao, w + 3 * DD, bb + 3 * Dz, nullptr, x, nullptr, BSz, Dz, Dz, 2);
        // cross-attention
        ln_kernel<WT><<<BSz, blk, 0, stream>>>(flag, want, x, dlg + (size_t)(l * 3 + 1) * Dz, dlb + (size_t)(l * 3 + 1) * Dz, xn);
        gemm(xn,   w + 4 * DD, bb + 4 * Dz, q, nullptr, nullptr, BSz, Dz, Dz, 0);
        gemm(memb, w + 5 * DD, bb + 5 * Dz, k, nullptr, nullptr, BSz, Dz, Dz, 0);
        gemm(memb, w + 6 * DD, bb + 6 * Dz, v, nullptr, nullptr, BSz, Dz, Dz, 0);
        attn(0);
        gemm(ao, w + 7 * DD, bb + 7 * Dz, nullptr, x, nullptr, BSz, Dz, Dz, 2);
        // ffn
        ln_kernel<WT><<<BSz, blk, 0, stream>>>(flag, want, x, dlg + (size_t)(l * 3 + 2) * Dz, dlb + (size_t)(l * 3 + 2) * Dz, xn);
        gemm(xn, dw1 + (size_t)l * Dz * FFz, db1 + (size_t)l * FFz, hbuf, nullptr, nullptr, BSz, FFz, Dz, 1);
        gemm(hbuf, dw2 + (size_t)l * FFz * Dz, db2 + (size_t)l * Dz, nullptr, x, nullptr, BSz, Dz, FFz, 2);
    }
    ln_kernel<WT><<<BSz, blk, 0, stream>>>(flag, want, x, dng, dnb, xn);

    // ================= output projection =================
    gemm(xn, outw, outb, nullptr, nullptr, out, BSz, Vz, Dz, 3);
}

// ---------------- launcher ----------------
extern "C" void kernel_launch(void* const* d_in, const int* in_sizes, int n_in,
                              void* d_out, int out_size, void* d_ws, size_t ws_size,
                              hipStream_t stream) {
    const size_t SD = (size_t)BSz * Dz;        // 3,145,728 elements
    char* wsb = (char*)d_ws;
    int*   flag = (int*)wsb;                                   // 256 B reserved
    float* x    = (float*)(wsb + 256);                         // SD fp32
    bf16*  xn   = (bf16*)(wsb + 256 + SD * 4);                 // SD bf16 (doubles as Vt)
    bf16*  memb = xn + SD;                                     // SD bf16
    bf16*  big  = memb + SD;                                   // 4*SD bf16
    bf16 *q = big, *k = big + SD, *v = big + 2 * SD, *ao = big + 3 * SD;
    bf16* hbuf = big;                                          // BSz*FFz == 4*SD, aliases q/k/v/ao
    // total ws use: 256 + 4*SD + 2*2*SD + 2*4*SD = ~50.4 MB

    detect_kernel<<<1, 256, 0, stream>>>((const unsigned short*)d_in[4], flag);
    run_net<bf16 >(d_in, 0, flag, x, xn, memb, q, k, v, ao, hbuf, (bf16*)d_out, stream);
    run_net<float>(d_in, 1, flag, x, xn, memb, q, k, v, ao, hbuf, (float*)d_out, stream);
}